// Round 6
// baseline (830.195 us; speedup 1.0000x reference)
//
#include <hip/hip_runtime.h>
#include <math.h>

#define N_NODES 50000
#define E_EDGES 800000
#define HDIM 256
#define NHEADS 8
#define HEADD 32
#define EDGED 3
#define NLAYERS 3

typedef unsigned int u32;
typedef unsigned char u8;
typedef unsigned short ushort_t;
typedef __attribute__((ext_vector_type(8))) short short8;
typedef __attribute__((ext_vector_type(8))) unsigned short ushort8v;
typedef __attribute__((ext_vector_type(4))) float float4v;
typedef __attribute__((ext_vector_type(2))) float float2v;

typedef __attribute__((address_space(1))) const void* gas_p;
typedef __attribute__((address_space(3))) void* las_p;

__device__ __forceinline__ float bf2f(ushort_t u) {
  union { u32 i; float f; } v;
  v.i = ((u32)u) << 16;
  return v.f;
}
// fp32 -> bf16 RNE
__device__ __forceinline__ ushort_t f2bf(float f) {
  u32 u = __float_as_uint(f);
  u = (u + 0x7FFF + ((u >> 16) & 1)) >> 16;
  return (ushort_t)u;
}
// fp32 -> fp8 e4m3 (HW convert)
__device__ __forceinline__ u8 f2f8(float f) {
  int p = __builtin_amdgcn_cvt_pk_fp8_f32(f, 0.f, 0, false);
  return (u8)(p & 0xFF);
}
// 4x fp8 e4m3 -> fp32 (HW convert; builtin returns ext-vector float2)
__device__ __forceinline__ void f8x4_to_f32(u32 v, float* out) {
  float2v a = __builtin_amdgcn_cvt_pk_f32_fp8((int)v, false);
  float2v b = __builtin_amdgcn_cvt_pk_f32_fp8((int)v, true);
  out[0] = a[0];
  out[1] = a[1];
  out[2] = b[0];
  out[3] = b[1];
}

// ---------------------------------------------------------------------------
// edge_index layout detection (int64 vs int32 staging)
// ---------------------------------------------------------------------------
__global__ __launch_bounds__(256) void detect_idx_k(const u32* __restrict__ w,
                                                    int* __restrict__ flag) {
  __shared__ u32 sm[256];
  u32 mx = 0;
  for (int k = threadIdx.x; k < 4096; k += 256) mx = max(mx, w[2 * k + 1]);
  sm[threadIdx.x] = mx;
  __syncthreads();
  for (int s = 128; s > 0; s >>= 1) {
    if (threadIdx.x < s)
      sm[threadIdx.x] = max(sm[threadIdx.x], sm[threadIdx.x + s]);
    __syncthreads();
  }
  if (threadIdx.x == 0) flag[0] = (sm[0] == 0) ? 1 : 0;
}

// convert + dst histogram fused
__global__ __launch_bounds__(256) void convert_hist_k(
    const u32* __restrict__ w, const int* __restrict__ flag,
    int* __restrict__ src32, int* __restrict__ dst32, int* __restrict__ dcnt,
    int E_) {
  int e = blockIdx.x * blockDim.x + threadIdx.x;
  if (e >= E_) return;
  int s, d;
  if (flag[0]) {
    s = (int)w[2 * e];
    d = (int)w[2 * (E_ + e)];
  } else {
    s = (int)w[e];
    d = (int)w[E_ + e];
  }
  src32[e] = s;
  dst32[e] = d;
  atomicAdd(&dcnt[d], 1);
}

__global__ __launch_bounds__(256) void scan1_k(const int* __restrict__ deg,
                                               int* __restrict__ scanned,
                                               int* __restrict__ bsum, int n) {
  __shared__ int tmp[256];
  int tid = threadIdx.x;
  int i = blockIdx.x * 256 + tid;
  tmp[tid] = (i < n) ? deg[i] : 0;
  __syncthreads();
  for (int off = 1; off < 256; off <<= 1) {
    int t = (tid >= off) ? tmp[tid - off] : 0;
    __syncthreads();
    tmp[tid] += t;
    __syncthreads();
  }
  if (i < n) scanned[i] = tmp[tid];
  if (tid == 255) bsum[blockIdx.x] = tmp[255];
}

__global__ __launch_bounds__(256) void scan2_k(int* __restrict__ bsum, int nb) {
  __shared__ int tmp[256];
  int tid = threadIdx.x;
  tmp[tid] = (tid < nb) ? bsum[tid] : 0;
  __syncthreads();
  for (int off = 1; off < 256; off <<= 1) {
    int t = (tid >= off) ? tmp[tid - off] : 0;
    __syncthreads();
    tmp[tid] += t;
    __syncthreads();
  }
  if (tid < nb) bsum[tid] = tmp[tid];
}

__global__ __launch_bounds__(256) void scan3_k(const int* __restrict__ scanned,
                                               const int* __restrict__ bsum,
                                               int* __restrict__ rowptr, int n) {
  int i = blockIdx.x * 256 + threadIdx.x;
  if (i < n)
    rowptr[i + 1] = scanned[i] + (blockIdx.x > 0 ? bsum[blockIdx.x - 1] : 0);
  if (i == 0) rowptr[0] = 0;
}

// CSR fill with packed (src, eorig) records
__global__ __launch_bounds__(256) void fill_k(
    const int* __restrict__ srcI, const int* __restrict__ dstI,
    const int* __restrict__ rowptr, int* __restrict__ cursor,
    int2* __restrict__ erec, int E_) {
  int e = blockIdx.x * blockDim.x + threadIdx.x;
  if (e >= E_) return;
  int d = dstI[e];
  int p = rowptr[d] + atomicAdd(&cursor[d], 1);
  erec[p] = make_int2(srcI[e], e);
}

// ---------------------------------------------------------------------------
// ALL weight prep in ONE launch: transposes (z<13), Wo@Wm fold (z 13..15),
// bias fold (z==16). The Wm transpose branch is restricted to k<256 so it
// does not race the wcomb branch, which is the sole writer of WmT[:,256:512).
// ---------------------------------------------------------------------------
__global__ __launch_bounds__(256) void wprep_all_k(
    const float* __restrict__ Wq, const float* __restrict__ Wk,
    const float* __restrict__ Wv, const float* __restrict__ Wm,
    const float* __restrict__ Wh1, const float* __restrict__ Wo,
    const float* __restrict__ bo, const float* __restrict__ bm,
    ushort_t* __restrict__ WqkvT, ushort_t* __restrict__ WmT,
    ushort_t* __restrict__ Wh1T, float* __restrict__ bcomb) {
  int z = blockIdx.z;
  if (z < 13) {
    const float* W;
    ushort_t* WT;
    int K, N;
    if (z < 9) {
      if (blockIdx.x >= 16) return;
      int l = z / 3, mm = z % 3;
      W = (mm == 0 ? Wq : mm == 1 ? Wk : Wv) + (size_t)l * 65536;
      WT = WqkvT + ((size_t)l * 3 + mm) * 65536;
      K = 256;
      N = 256;
    } else if (z < 12) {
      // only the k<256 (identity) half of WmT; wcomb writes [256,512)
      if (blockIdx.x >= 16) return;
      int l = z - 9;
      W = Wm + (size_t)l * 131072;
      WT = WmT + (size_t)l * 131072;
      K = 512;
      N = 256;
    } else {
      if (blockIdx.x >= 16 || blockIdx.y >= 2) return;
      W = Wh1;
      WT = Wh1T;
      K = 256;
      N = 128;
    }
    __shared__ float t[64][17];
    int k0 = blockIdx.x * 16, n0 = blockIdx.y * 64;
    int tid = threadIdx.x;
    int r = tid >> 6, c = tid & 63;
#pragma unroll
    for (int i = 0; i < 4; ++i)
      t[c][r + 4 * i] = W[(size_t)(k0 + r + 4 * i) * N + n0 + c];
    __syncthreads();
    int nn = tid >> 2, j4 = (tid & 3) * 4;
    ushort4 o;
    o.x = f2bf(t[nn][j4 + 0]);
    o.y = f2bf(t[nn][j4 + 1]);
    o.z = f2bf(t[nn][j4 + 2]);
    o.w = f2bf(t[nn][j4 + 3]);
    *(ushort4*)&WT[(size_t)(n0 + nn) * K + k0 + j4] = o;
  } else if (z < 16) {
    // wcomb: WmT[l][n][256+k] = bf16( sum_j Wo[l][k][j] * Wm[l][256+j][n] )
    if (blockIdx.x >= 4 || blockIdx.y >= 4) return;
    int l = z - 13;
    const float* A = Wo + (size_t)l * 65536;
    const float* B = Wm + (size_t)l * 131072 + 65536;
    ushort_t* Out = WmT + (size_t)l * 131072;
    __shared__ float As[16][64];
    __shared__ float Bs[16][64];
    int tid = threadIdx.x;
    int tx = tid & 15, ty = tid >> 4;
    int k0 = blockIdx.x * 64, n0 = blockIdx.y * 64;
    float acc[4][4] = {};
    int arow = tid >> 2;
    int aj = (tid & 3) * 4;
    int brow = tid >> 4;
    int bcol = (tid & 15) * 4;
    for (int j0 = 0; j0 < 256; j0 += 16) {
      float4 av = *(const float4*)(A + (size_t)(k0 + arow) * 256 + j0 + aj);
      As[aj + 0][arow] = av.x;
      As[aj + 1][arow] = av.y;
      As[aj + 2][arow] = av.z;
      As[aj + 3][arow] = av.w;
      *(float4*)&Bs[brow][bcol] =
          *(const float4*)(B + (size_t)(j0 + brow) * 256 + n0 + bcol);
      __syncthreads();
#pragma unroll
      for (int j = 0; j < 16; ++j) {
        float a[4], bb[4];
#pragma unroll
        for (int i = 0; i < 4; ++i) a[i] = As[j][ty * 4 + i];
#pragma unroll
        for (int jj = 0; jj < 4; ++jj) bb[jj] = Bs[j][tx * 4 + jj];
#pragma unroll
        for (int i = 0; i < 4; ++i)
#pragma unroll
          for (int jj = 0; jj < 4; ++jj) acc[i][jj] += a[i] * bb[jj];
      }
      __syncthreads();
    }
#pragma unroll
    for (int i = 0; i < 4; ++i)
#pragma unroll
      for (int jj = 0; jj < 4; ++jj) {
        int k = k0 + ty * 4 + i, nn = n0 + tx * 4 + jj;
        Out[(size_t)nn * 512 + 256 + k] = f2bf(acc[i][jj]);
      }
  } else {
    // bcomb[l][n] = bm[l][n] + sum_j bo[l][j] * Wm[l][256+j][n]
    if (blockIdx.x >= 3 || blockIdx.y != 0) return;
    int l = blockIdx.x;
    int nn = threadIdx.x;
    const float* Bw = Wm + (size_t)l * 131072 + 65536;
    const float* bol = bo + l * 256;
    float acc = bm[l * 256 + nn];
    for (int j = 0; j < 256; ++j) acc += bol[j] * Bw[(size_t)j * 256 + nn];
    bcomb[l * 256 + nn] = acc;
  }
}

// ---------------------------------------------------------------------------
// Input projection: hbf = bf16(relu(x @ W_in + b_in))
// ---------------------------------------------------------------------------
__global__ __launch_bounds__(256) void input_proj_k(
    const float* __restrict__ x, const float* __restrict__ W,
    const float* __restrict__ b, ushort_t* __restrict__ hbf, int n) {
  __shared__ float ws[10 * 256];
  __shared__ float bs[256];
  int tid = threadIdx.x;
  for (int i = tid; i < 2560; i += 256) ws[i] = W[i];
  bs[tid] = b[tid];
  __syncthreads();
  int row0 = blockIdx.x * 32;
  for (int rr = 0; rr < 32; ++rr) {
    int row = row0 + rr;
    if (row >= n) break;
    float acc = bs[tid];
#pragma unroll
    for (int i = 0; i < 10; ++i) acc += x[row * 10 + i] * ws[i * 256 + tid];
    hbf[(size_t)row * 256 + tid] = f2bf(fmaxf(acc, 0.f));
  }
}

// ---------------------------------------------------------------------------
// QKV GEMM v3: A-LDS-resident. Block = 128 rows x 384 cols (grid 2 x 391).
// A[128x256] (64 KB) staged ONCE per block; loop 3 col-tiles x 4 K-chunks
// staging only B (16 KB/chunk, L2-resident). Cuts A-read traffic per call
// from 154 MB (6x re-stage) to 51 MB (2x). Same MFMA fragment pattern as
// the R10 core (32 rows/wave keeps ds_read:MFMA balanced). Dual-dtype
// epilogue: cols [0,256) -> bf16 Qbf; cols [256,768) -> fp8 KV8.
// ---------------------------------------------------------------------------
__global__ __launch_bounds__(256) void gemm_qkv_k(
    const ushort_t* __restrict__ A1, const ushort_t* __restrict__ BT,
    ushort_t* __restrict__ Qbf, u8* __restrict__ KV8, int M) {
  __shared__ __align__(16) ushort_t Als[128 * 256];  // 64 KB (A-resident)
  __shared__ __align__(16) ushort_t Bls[128 * 64];   // 16 KB per K-chunk
  int tid = threadIdx.x;
  int lane = tid & 63, w = tid >> 6;
  int quad = lane >> 4, m = lane & 15;
  int row0 = blockIdx.y * 128;
  int colbase = blockIdx.x * 384;

  // ---- stage A once: [row][K] 128 x 256, linear in tid order ----
  {
    int arow = tid >> 5;        // 0..7 within one 4 KB issue
    int akc = (tid & 31) * 8;   // ushort offset within row
    char* alsb = (char*)Als + w * 1024;
#pragma unroll
    for (int q = 0; q < 16; ++q) {
      int r = row0 + q * 8 + arow;
      if (r < M) {
        const ushort_t* g = A1 + (size_t)r * 256 + akc;
        __builtin_amdgcn_global_load_lds((gas_p)g, (las_p)(alsb + q * 4096),
                                         16, 0, 0);
      }
    }
  }

  int srow = tid >> 3;
  int skc = (tid & 7) * 8;
  char* blsb = (char*)Bls + w * 1024;

  for (int cj = 0; cj < 3; ++cj) {
    int col0 = colbase + cj * 128;
    float4v acc[2][8];
#pragma unroll
    for (int t = 0; t < 2; ++t)
#pragma unroll
      for (int j = 0; j < 8; ++j) acc[t][j] = (float4v){0.f, 0.f, 0.f, 0.f};

    for (int k0 = 0; k0 < 256; k0 += 64) {
#pragma unroll
      for (int q = 0; q < 4; ++q) {
        const ushort_t* g =
            BT + (size_t)(col0 + q * 32 + srow) * 256 + k0 + skc;
        __builtin_amdgcn_global_load_lds((gas_p)g, (las_p)(blsb + q * 4096),
                                         16, 0, 0);
      }
      __syncthreads();  // waits B chunk (and A on first pass)
#pragma unroll
      for (int ks = 0; ks < 64; ks += 32) {
        short8 a0 =
            *(const short8*)&Als[(w * 32 + m) * 256 + k0 + ks + quad * 8];
        short8 a1 =
            *(const short8*)&Als[(w * 32 + 16 + m) * 256 + k0 + ks + quad * 8];
#pragma unroll
        for (int j = 0; j < 8; ++j) {
          short8 bj = *(const short8*)&Bls[(16 * j + m) * 64 + ks + quad * 8];
          acc[0][j] = __builtin_amdgcn_mfma_f32_16x16x32_bf16(a0, bj,
                                                              acc[0][j], 0, 0, 0);
          acc[1][j] = __builtin_amdgcn_mfma_f32_16x16x32_bf16(a1, bj,
                                                              acc[1][j], 0, 0, 0);
        }
      }
      __syncthreads();  // Bls consumed; safe to restage
    }

#pragma unroll
    for (int t = 0; t < 2; ++t) {
#pragma unroll
      for (int j = 0; j < 8; ++j) {
        int col = col0 + 16 * j + m;
#pragma unroll
        for (int rr = 0; rr < 4; ++rr) {
          int row = row0 + w * 32 + 16 * t + quad * 4 + rr;
          if (row >= M) continue;
          float v = acc[t][j][rr];
          if (col < 256)
            Qbf[(size_t)row * 256 + col] = f2bf(v);
          else
            KV8[(size_t)row * 512 + (col - 256)] = f2f8(v);
        }
      }
    }
  }
}

// ---------------------------------------------------------------------------
// Wm GEMM + residual + LayerNorm FUSED (R14-proven), 64x256 tile, K=512.
// ---------------------------------------------------------------------------
__global__ __launch_bounds__(256) void gemm_ln_k(
    ushort_t* __restrict__ hbf, const ushort_t* __restrict__ aggbf,
    const ushort_t* __restrict__ BT, const float* __restrict__ bcomb,
    const float* __restrict__ gamma, const float* __restrict__ beta, int M) {
  __shared__ __align__(16) ushort_t Als[64 * 64];   // 8 KB
  __shared__ __align__(16) ushort_t Bls[256 * 64];  // 32 KB
  int tid = threadIdx.x;
  int lane = tid & 63, w = tid >> 6;
  int quad = lane >> 4, m = lane & 15;
  int row0 = blockIdx.x * 64;
  float4v acc[16];
#pragma unroll
  for (int j = 0; j < 16; ++j) acc[j] = (float4v){0.f, 0.f, 0.f, 0.f};

  int srow = tid >> 3;
  int skc = (tid & 7) * 8;
  char* alsb = (char*)Als + w * 1024;
  char* blsb = (char*)Bls + w * 1024;

  for (int k0 = 0; k0 < 512; k0 += 64) {
    const ushort_t* Ap = (k0 < 256) ? (const ushort_t*)hbf : aggbf;
    int kk = k0 & 255;
#pragma unroll
    for (int q = 0; q < 2; ++q) {
      int r = row0 + q * 32 + srow;
      if (r < M) {
        const ushort_t* g = Ap + (size_t)r * 256 + kk + skc;
        __builtin_amdgcn_global_load_lds((gas_p)g, (las_p)(alsb + q * 4096),
                                         16, 0, 0);
      }
    }
#pragma unroll
    for (int q = 0; q < 8; ++q) {
      const ushort_t* g = BT + (size_t)(q * 32 + srow) * 512 + k0 + skc;
      __builtin_amdgcn_global_load_lds((gas_p)g, (las_p)(blsb + q * 4096), 16,
                                       0, 0);
    }
    __syncthreads();
#pragma unroll
    for (int ks = 0; ks < 64; ks += 32) {
      short8 a = *(const short8*)&Als[(w * 16 + m) * 64 + ks + quad * 8];
#pragma unroll
      for (int j = 0; j < 16; ++j) {
        short8 bj = *(const short8*)&Bls[(16 * j + m) * 64 + ks + quad * 8];
        acc[j] = __builtin_amdgcn_mfma_f32_16x16x32_bf16(a, bj, acc[j], 0, 0, 0);
      }
    }
    __syncthreads();
  }

#pragma unroll
  for (int rr = 0; rr < 4; ++rr) {
    int row = row0 + w * 16 + quad * 4 + rr;
    if (row >= M) continue;
    float sv[16];
    float sum = 0.f, sq = 0.f;
#pragma unroll
    for (int j = 0; j < 16; ++j) {
      int col = m + 16 * j;
      float u = fmaxf(acc[j][rr] + bcomb[col], 0.f);
      float s = bf2f(hbf[(size_t)row * 256 + col]) + u;
      sv[j] = s;
      sum += s;
      sq += s * s;
    }
#pragma unroll
    for (int off = 1; off < 16; off <<= 1) {
      sum += __shfl_xor(sum, off);
      sq += __shfl_xor(sq, off);
    }
    float mean = sum * (1.f / 256.f);
    float var = sq * (1.f / 256.f) - mean * mean;
    float r = rsqrtf(var + 1e-5f);
#pragma unroll
    for (int j = 0; j < 16; ++j) {
      int col = m + 16 * j;
      float o = (sv[j] - mean) * r * gamma[col] + beta[col];
      hbf[(size_t)row * 256 + col] = f2bf(o);
    }
  }
}

// ---------------------------------------------------------------------------
// Output head FUSED (R15-proven)
// ---------------------------------------------------------------------------
__global__ __launch_bounds__(256) void head_fused_k(
    const ushort_t* __restrict__ hbf, const ushort_t* __restrict__ W1T,
    const float* __restrict__ b1, const float* __restrict__ W2,
    const float* __restrict__ b2, float* __restrict__ out, int M) {
  __shared__ __align__(16) ushort_t Als[64 * 64];
  __shared__ __align__(16) ushort_t Bls[128 * 64];
  int tid = threadIdx.x;
  int lane = tid & 63, w = tid >> 6;
  int quad = lane >> 4, m = lane & 15;
  int row0 = blockIdx.x * 64;
  float4v acc[8];
#pragma unroll
  for (int j = 0; j < 8; ++j) acc[j] = (float4v){0.f, 0.f, 0.f, 0.f};

  int srow = tid >> 3;
  int skc = (tid & 7) * 8;
  char* alsb = (char*)Als + w * 1024;
  char* blsb = (char*)Bls + w * 1024;

  for (int k0 = 0; k0 < 256; k0 += 64) {
#pragma unroll
    for (int q = 0; q < 2; ++q) {
      int r = row0 + q * 32 + srow;
      if (r < M) {
        const ushort_t* g = hbf + (size_t)r * 256 + k0 + skc;
        __builtin_amdgcn_global_load_lds((gas_p)g, (las_p)(alsb + q * 4096),
                                         16, 0, 0);
      }
    }
#pragma unroll
    for (int q = 0; q < 4; ++q) {
      const ushort_t* g = W1T + (size_t)(q * 32 + srow) * 256 + k0 + skc;
      __builtin_amdgcn_global_load_lds((gas_p)g, (las_p)(blsb + q * 4096), 16,
                                       0, 0);
    }
    __syncthreads();
#pragma unroll
    for (int ks = 0; ks < 64; ks += 32) {
      short8 a = *(const short8*)&Als[(w * 16 + m) * 64 + ks + quad * 8];
#pragma unroll
      for (int j = 0; j < 8; ++j) {
        short8 bj = *(const short8*)&Bls[(16 * j + m) * 64 + ks + quad * 8];
        acc[j] = __builtin_amdgcn_mfma_f32_16x16x32_bf16(a, bj, acc[j], 0, 0, 0);
      }
    }
    __syncthreads();
  }

#pragma unroll
  for (int rr = 0; rr < 4; ++rr) {
    int row = row0 + w * 16 + quad * 4 + rr;
    if (row >= M) continue;
    float p = 0.f;
#pragma unroll
    for (int j = 0; j < 8; ++j) {
      int col = m + 16 * j;
      float t = fmaxf(acc[j][rr] + b1[col], 0.f);
      p += t * W2[col];
    }
#pragma unroll
    for (int off = 1; off < 16; off <<= 1) p += __shfl_xor(p, off);
    if (m == 0) out[row] = p + b2[0];
  }
}

// ---------------------------------------------------------------------------
// FUSED edge phase (R0-proven form, restored). fp8 K/V gathers, NO online
// max: softmax shift-invariance cancels the reference's global-max
// subtraction exactly; logits bounded, fp32 exp safe. This kernel is
// BANDWIDTH-bound on the L2-miss gather path (~3.3 TB/s, ~1.2x compulsory
// traffic) — R1's 4-deep ILP restructure was re-serialized by the compiler
// (VGPR stayed 28) and its tail-clamp added +4% fetch for +3% time.
// Degree-0: loop skipped -> l=0 -> clip(1e-12) -> agg=0, as the reference.
// ---------------------------------------------------------------------------
__global__ __launch_bounds__(256) void node_fused_k(
    const ushort_t* __restrict__ Q, const u8* __restrict__ KV8,
    const float* __restrict__ ea, const float* __restrict__ We_l,
    const int* __restrict__ rowptr, const int2* __restrict__ erec,
    ushort_t* __restrict__ agg, int n) {
  int node = (blockIdx.x * blockDim.x + threadIdx.x) >> 6;
  if (node >= n) return;
  int lane = threadIdx.x & 63;
  int hl = lane & 31;
  int slot = lane >> 5;
  ushort8v qu = *((const ushort8v*)(Q + (size_t)node * 256) + hl);
  float q[8];
#pragma unroll
  for (int i = 0; i < 8; ++i) q[i] = bf2f(qu[i]);
  int start = rowptr[node], end = rowptr[node + 1];
  int hh = hl >> 2;
  float w0 = We_l[0 * 8 + hh], w1 = We_l[1 * 8 + hh], w2 = We_l[2 * 8 + hh];
  float l = 0.f;
  float acc[8];
#pragma unroll
  for (int i = 0; i < 8; ++i) acc[i] = 0.f;

  int iters = (end - start + 1) >> 1;
  for (int it = 0; it < iters; ++it) {
    int p = start + 2 * it + slot;
    if (p < end) {
      int2 er = erec[p];
      const u8* base = KV8 + (size_t)er.x * 512;
      uint2 ku = *((const uint2*)base + hl);
      uint2 vu = *((const uint2*)(base + 256) + hl);
      float kf[8], vf[8];
      f8x4_to_f32(ku.x, kf);
      f8x4_to_f32(ku.y, kf + 4);
      f8x4_to_f32(vu.x, vf);
      f8x4_to_f32(vu.y, vf + 4);
      float d = 0.f;
#pragma unroll
      for (int i = 0; i < 8; ++i) d += q[i] * kf[i];
      d += __shfl_xor(d, 1);
      d += __shfl_xor(d, 2);
      float bias = ea[(size_t)er.y * 3 + 0] * w0 +
                   ea[(size_t)er.y * 3 + 1] * w1 +
                   ea[(size_t)er.y * 3 + 2] * w2;
      float a = d * 0.17677669529663687f + bias;  // 1/sqrt(32)
      a = (a > 0.f) ? a : 0.2f * a;               // leaky_relu 0.2
      float wv = __expf(a);
      l += wv;
#pragma unroll
      for (int i = 0; i < 8; ++i) acc[i] += vf[i] * wv;
    }
  }
  // merge the two half-wave partial sums
  l += __shfl_xor(l, 32);
  float inv = 1.f / fmaxf(l, 1e-12f);
  ushort8v o;
#pragma unroll
  for (int i = 0; i < 8; ++i) {
    float v = (acc[i] + __shfl_xor(acc[i], 32)) * inv;
    o[i] = f2bf(v);
  }
  if (slot == 0)
    *((ushort8v*)(agg + (size_t)node * 256) + hl) = o;
}

// ---------------------------------------------------------------------------
extern "C" void kernel_launch(void* const* d_in, const int* in_sizes, int n_in,
                              void* d_out, int out_size, void* d_ws,
                              size_t ws_size, hipStream_t stream) {
  const float* x = (const float*)d_in[0];
  const float* edge_attr = (const float*)d_in[1];
  const float* W_in = (const float*)d_in[2];
  const float* b_in = (const float*)d_in[3];
  const float* Wq = (const float*)d_in[4];
  const float* Wk = (const float*)d_in[5];
  const float* Wv = (const float*)d_in[6];
  const float* We = (const float*)d_in[7];
  const float* Wo = (const float*)d_in[8];
  const float* bo = (const float*)d_in[9];
  const float* Wm = (const float*)d_in[10];
  const float* bm = (const float*)d_in[11];
  const float* gamma = (const float*)d_in[12];
  const float* beta = (const float*)d_in[13];
  const float* W_h1 = (const float*)d_in[14];
  const float* b_h1 = (const float*)d_in[15];
  const float* W_h2 = (const float*)d_in[16];
  const float* b_h2 = (const float*)d_in[17];
  const u32* eidx_w = (const u32*)d_in[18];

  // ws layout (~112 MB)
  float* ws = (float*)d_ws;
  const size_t NH_ = (size_t)N_NODES * HDIM;
  ushort_t* hbf = (ushort_t*)ws;            // N x 256 bf16, persists
  ushort_t* Qbf = hbf + NH_;                // N x 256 bf16
  u8* KV8 = (u8*)(Qbf + NH_);               // N x 512 fp8 (K | V)
  ushort_t* aggbf = (ushort_t*)(KV8 + (size_t)N_NODES * 512);  // N x 256
  int* idxflag = (int*)(aggbf + NH_);
  int2* erec = (int2*)(idxflag + 2);        // E packed (src, eorig)
  int* rowptr = (int*)(erec + E_EDGES);     // N+1
  int* dcnt = rowptr + N_NODES + 1;         // N (hist)
  int* cursor = dcnt + N_NODES;             // N (fill) — zeroed together
  int* scanned = cursor + N_NODES;          // N
  int* bsum = scanned + N_NODES;            // 256
  float* bcomb = (float*)(bsum + 256);      // 3 x 256 fp32
  ushort_t* WT = (ushort_t*)(bcomb + 3 * 256);
  const size_t W64K = (size_t)HDIM * HDIM;
  const size_t W128K = (size_t)2 * HDIM * HDIM;
  ushort_t* WqkvT = WT;                     // 3 layers x (768 x 256)
  ushort_t* WmT = WqkvT + 3 * 3 * W64K;     // 3 layers x (256 x 512)
  ushort_t* Wh1T = WmT + 3 * W128K;
  // transient: consumed by fill_k before the first QKV gemm writes Qbf
  int* srcI = (int*)Qbf;
  int* dstI = srcI + E_EDGES;

  detect_idx_k<<<1, 256, 0, stream>>>(eidx_w, idxflag);
  hipMemsetAsync(dcnt, 0, (size_t)2 * N_NODES * sizeof(int), stream);
  convert_hist_k<<<(E_EDGES + 255) / 256, 256, 0, stream>>>(
      eidx_w, idxflag, srcI, dstI, dcnt, E_EDGES);
  const int nsb = (N_NODES + 255) / 256;
  scan1_k<<<nsb, 256, 0, stream>>>(dcnt, scanned, bsum, N_NODES);
  scan2_k<<<1, 256, 0, stream>>>(bsum, nsb);
  scan3_k<<<nsb, 256, 0, stream>>>(scanned, bsum, rowptr, N_NODES);
  fill_k<<<(E_EDGES + 255) / 256, 256, 0, stream>>>(
      srcI, dstI, rowptr, cursor, erec, E_EDGES);

  // all weight prep in one launch (transposes + Wo fold + bias fold)
  wprep_all_k<<<dim3(16, 4, 17), 256, 0, stream>>>(
      Wq, Wk, Wv, Wm, W_h1, Wo, bo, bm, WqkvT, WmT, Wh1T, bcomb);

  input_proj_k<<<(N_NODES + 31) / 32, 256, 0, stream>>>(x, W_in, b_in, hbf,
                                                        N_NODES);
  dim3 gqkv(2, (N_NODES + 127) / 128);  // (2, 391), A-resident blocks
  const int gml = (N_NODES + 63) / 64;  // 782
  const int nodewave_grid = (N_NODES * 64 + 255) / 256;

  for (int l = 0; l < NLAYERS; ++l) {
    const float* We_l = We + (size_t)l * EDGED * NHEADS;

    // QKV = hbf @ [Wq|Wk|Wv] -> Q bf16, K/V fp8 (A-resident, 128x384 block)
    gemm_qkv_k<<<gqkv, 256, 0, stream>>>(
        hbf, WqkvT + (size_t)l * 3 * W64K, Qbf, KV8, N_NODES);
    // fused attention + softmax + aggregation (fp8 K/V gathers)
    node_fused_k<<<nodewave_grid, 256, 0, stream>>>(
        Qbf, KV8, edge_attr, We_l, rowptr, erec, aggbf, N_NODES);
    // hbf = LN(hbf + relu([hbf|agg]@Wm' + bcomb)) — GEMM+LN fused, in-place
    gemm_ln_k<<<gml, 256, 0, stream>>>(
        hbf, aggbf, WmT + (size_t)l * W128K, bcomb + l * 256,
        gamma + (size_t)l * HDIM, beta + (size_t)l * HDIM, N_NODES);
  }
  // fused output head
  head_fused_k<<<gml, 256, 0, stream>>>(hbf, Wh1T, b_h1, W_h2, b_h2,
                                        (float*)d_out, N_NODES);
}

// Round 8
// 758.311 us; speedup vs baseline: 1.0948x; 1.0948x over previous
//
#include <hip/hip_runtime.h>
#include <math.h>

#define N_NODES 50000
#define E_EDGES 800000
#define HDIM 256
#define NHEADS 8
#define HEADD 32
#define EDGED 3
#define NLAYERS 3

typedef unsigned int u32;
typedef unsigned char u8;
typedef unsigned short ushort_t;
typedef __attribute__((ext_vector_type(8))) short short8;
typedef __attribute__((ext_vector_type(8))) unsigned short ushort8v;
typedef __attribute__((ext_vector_type(4))) float float4v;
typedef __attribute__((ext_vector_type(2))) float float2v;

typedef __attribute__((address_space(1))) const void* gas_p;
typedef __attribute__((address_space(3))) void* las_p;

__device__ __forceinline__ float bf2f(ushort_t u) {
  union { u32 i; float f; } v;
  v.i = ((u32)u) << 16;
  return v.f;
}
// fp32 -> bf16 RNE
__device__ __forceinline__ ushort_t f2bf(float f) {
  u32 u = __float_as_uint(f);
  u = (u + 0x7FFF + ((u >> 16) & 1)) >> 16;
  return (ushort_t)u;
}
// fp32 -> fp8 e4m3 (HW convert)
__device__ __forceinline__ u8 f2f8(float f) {
  int p = __builtin_amdgcn_cvt_pk_fp8_f32(f, 0.f, 0, false);
  return (u8)(p & 0xFF);
}
// 4x fp8 e4m3 -> fp32 (HW convert; builtin returns ext-vector float2)
__device__ __forceinline__ void f8x4_to_f32(u32 v, float* out) {
  float2v a = __builtin_amdgcn_cvt_pk_f32_fp8((int)v, false);
  float2v b = __builtin_amdgcn_cvt_pk_f32_fp8((int)v, true);
  out[0] = a[0];
  out[1] = a[1];
  out[2] = b[0];
  out[3] = b[1];
}

// ---------------------------------------------------------------------------
// edge_index layout detection (int64 vs int32 staging)
// ---------------------------------------------------------------------------
__global__ __launch_bounds__(256) void detect_idx_k(const u32* __restrict__ w,
                                                    int* __restrict__ flag) {
  __shared__ u32 sm[256];
  u32 mx = 0;
  for (int k = threadIdx.x; k < 4096; k += 256) mx = max(mx, w[2 * k + 1]);
  sm[threadIdx.x] = mx;
  __syncthreads();
  for (int s = 128; s > 0; s >>= 1) {
    if (threadIdx.x < s)
      sm[threadIdx.x] = max(sm[threadIdx.x], sm[threadIdx.x + s]);
    __syncthreads();
  }
  if (threadIdx.x == 0) flag[0] = (sm[0] == 0) ? 1 : 0;
}

// convert + dst histogram fused
__global__ __launch_bounds__(256) void convert_hist_k(
    const u32* __restrict__ w, const int* __restrict__ flag,
    int* __restrict__ src32, int* __restrict__ dst32, int* __restrict__ dcnt,
    int E_) {
  int e = blockIdx.x * blockDim.x + threadIdx.x;
  if (e >= E_) return;
  int s, d;
  if (flag[0]) {
    s = (int)w[2 * e];
    d = (int)w[2 * (E_ + e)];
  } else {
    s = (int)w[e];
    d = (int)w[E_ + e];
  }
  src32[e] = s;
  dst32[e] = d;
  atomicAdd(&dcnt[d], 1);
}

__global__ __launch_bounds__(256) void scan1_k(const int* __restrict__ deg,
                                               int* __restrict__ scanned,
                                               int* __restrict__ bsum, int n) {
  __shared__ int tmp[256];
  int tid = threadIdx.x;
  int i = blockIdx.x * 256 + tid;
  tmp[tid] = (i < n) ? deg[i] : 0;
  __syncthreads();
  for (int off = 1; off < 256; off <<= 1) {
    int t = (tid >= off) ? tmp[tid - off] : 0;
    __syncthreads();
    tmp[tid] += t;
    __syncthreads();
  }
  if (i < n) scanned[i] = tmp[tid];
  if (tid == 255) bsum[blockIdx.x] = tmp[255];
}

__global__ __launch_bounds__(256) void scan2_k(int* __restrict__ bsum, int nb) {
  __shared__ int tmp[256];
  int tid = threadIdx.x;
  tmp[tid] = (tid < nb) ? bsum[tid] : 0;
  __syncthreads();
  for (int off = 1; off < 256; off <<= 1) {
    int t = (tid >= off) ? tmp[tid - off] : 0;
    __syncthreads();
    tmp[tid] += t;
    __syncthreads();
  }
  if (tid < nb) bsum[tid] = tmp[tid];
}

__global__ __launch_bounds__(256) void scan3_k(const int* __restrict__ scanned,
                                               const int* __restrict__ bsum,
                                               int* __restrict__ rowptr, int n) {
  int i = blockIdx.x * 256 + threadIdx.x;
  if (i < n)
    rowptr[i + 1] = scanned[i] + (blockIdx.x > 0 ? bsum[blockIdx.x - 1] : 0);
  if (i == 0) rowptr[0] = 0;
}

// CSR fill with packed 16-B records: {src, ea0|ea1 (bf16), ea2 (bf16), 0}.
// Embedding the edge features kills node_fused's random 64-B-line pulls at
// ea[er.y*3] (~40-50 MB/call of the 244 MB FETCH). ea read here is
// e-sequential (streaming); the record scatter writes the same line count
// as the previous 8-B scatter. bf16 ea rounding -> bias err ~6e-4 on
// logits, well inside the absmax margin.
__global__ __launch_bounds__(256) void fill_k(
    const int* __restrict__ srcI, const int* __restrict__ dstI,
    const float* __restrict__ ea, const int* __restrict__ rowptr,
    int* __restrict__ cursor, int4* __restrict__ erec, int E_) {
  int e = blockIdx.x * blockDim.x + threadIdx.x;
  if (e >= E_) return;
  int d = dstI[e];
  int p = rowptr[d] + atomicAdd(&cursor[d], 1);
  float a0 = ea[3 * (size_t)e + 0];
  float a1 = ea[3 * (size_t)e + 1];
  float a2 = ea[3 * (size_t)e + 2];
  int4 r;
  r.x = srcI[e];
  r.y = (int)((u32)f2bf(a0) | ((u32)f2bf(a1) << 16));
  r.z = (int)(u32)f2bf(a2);
  r.w = 0;
  erec[p] = r;
}

// ---------------------------------------------------------------------------
// ALL weight transposes in one launch (R15-proven, exact R0 form).
// ---------------------------------------------------------------------------
__global__ __launch_bounds__(256) void wtrans_all_k(
    const float* __restrict__ Wq, const float* __restrict__ Wk,
    const float* __restrict__ Wv, const float* __restrict__ Wm,
    const float* __restrict__ Wh1, ushort_t* __restrict__ WqkvT,
    ushort_t* __restrict__ WmT, ushort_t* __restrict__ Wh1T) {
  int z = blockIdx.z;
  const float* W;
  ushort_t* WT;
  int K, N;
  if (z < 9) {
    if (blockIdx.x >= 16) return;
    int l = z / 3, m = z % 3;
    W = (m == 0 ? Wq : m == 1 ? Wk : Wv) + (size_t)l * 65536;
    WT = WqkvT + ((size_t)l * 3 + m) * 65536;
    K = 256;
    N = 256;
  } else if (z < 12) {
    int l = z - 9;
    W = Wm + (size_t)l * 131072;
    WT = WmT + (size_t)l * 131072;
    K = 512;
    N = 256;
  } else {
    if (blockIdx.x >= 16 || blockIdx.y >= 2) return;
    W = Wh1;
    WT = Wh1T;
    K = 256;
    N = 128;
  }
  __shared__ float t[64][17];
  int k0 = blockIdx.x * 16, n0 = blockIdx.y * 64;
  int tid = threadIdx.x;
  int r = tid >> 6, c = tid & 63;
#pragma unroll
  for (int i = 0; i < 4; ++i)
    t[c][r + 4 * i] = W[(size_t)(k0 + r + 4 * i) * N + n0 + c];
  __syncthreads();
  int n = tid >> 2, j4 = (tid & 3) * 4;
  ushort4 o;
  o.x = f2bf(t[n][j4 + 0]);
  o.y = f2bf(t[n][j4 + 1]);
  o.z = f2bf(t[n][j4 + 2]);
  o.w = f2bf(t[n][j4 + 3]);
  *(ushort4*)&WT[(size_t)(n0 + n) * K + k0 + j4] = o;
}

// ---------------------------------------------------------------------------
// Wo->Wm folding (R12-proven, exact R0 form)
// ---------------------------------------------------------------------------
__global__ __launch_bounds__(256) void wcomb_k(const float* __restrict__ Wo,
                                               const float* __restrict__ Wm,
                                               ushort_t* __restrict__ WmT) {
  int l = blockIdx.z;
  const float* A = Wo + (size_t)l * 65536;
  const float* B = Wm + (size_t)l * 131072 + 65536;
  ushort_t* Out = WmT + (size_t)l * 131072;
  __shared__ float As[16][64];
  __shared__ float Bs[16][64];
  int tid = threadIdx.x;
  int tx = tid & 15, ty = tid >> 4;
  int k0 = blockIdx.x * 64, n0 = blockIdx.y * 64;
  float acc[4][4] = {};
  int arow = tid >> 2;
  int aj = (tid & 3) * 4;
  int brow = tid >> 4;
  int bcol = (tid & 15) * 4;
  for (int j0 = 0; j0 < 256; j0 += 16) {
    float4 av = *(const float4*)(A + (size_t)(k0 + arow) * 256 + j0 + aj);
    As[aj + 0][arow] = av.x;
    As[aj + 1][arow] = av.y;
    As[aj + 2][arow] = av.z;
    As[aj + 3][arow] = av.w;
    *(float4*)&Bs[brow][bcol] =
        *(const float4*)(B + (size_t)(j0 + brow) * 256 + n0 + bcol);
    __syncthreads();
#pragma unroll
    for (int j = 0; j < 16; ++j) {
      float a[4], bb[4];
#pragma unroll
      for (int i = 0; i < 4; ++i) a[i] = As[j][ty * 4 + i];
#pragma unroll
      for (int jj = 0; jj < 4; ++jj) bb[jj] = Bs[j][tx * 4 + jj];
#pragma unroll
      for (int i = 0; i < 4; ++i)
#pragma unroll
        for (int jj = 0; jj < 4; ++jj) acc[i][jj] += a[i] * bb[jj];
    }
    __syncthreads();
  }
#pragma unroll
  for (int i = 0; i < 4; ++i)
#pragma unroll
    for (int jj = 0; jj < 4; ++jj) {
      int k = k0 + ty * 4 + i, n = n0 + tx * 4 + jj;
      Out[(size_t)n * 512 + 256 + k] = f2bf(acc[i][jj]);
    }
}

// bcomb[l][n] = bm[l][n] + sum_j bo[l][j] * Wm[l][256+j][n]
__global__ __launch_bounds__(256) void bcomb_k(const float* __restrict__ bo,
                                               const float* __restrict__ bm,
                                               const float* __restrict__ Wm,
                                               float* __restrict__ bcomb) {
  int l = blockIdx.z;
  int n = threadIdx.x;
  const float* Bw = Wm + (size_t)l * 131072 + 65536;
  const float* bol = bo + l * 256;
  float acc = bm[l * 256 + n];
  for (int j = 0; j < 256; ++j) acc += bol[j] * Bw[(size_t)j * 256 + n];
  bcomb[l * 256 + n] = acc;
}

// ---------------------------------------------------------------------------
// Input projection: hbf = bf16(relu(x @ W_in + b_in))
// ---------------------------------------------------------------------------
__global__ __launch_bounds__(256) void input_proj_k(
    const float* __restrict__ x, const float* __restrict__ W,
    const float* __restrict__ b, ushort_t* __restrict__ hbf, int n) {
  __shared__ float ws[10 * 256];
  __shared__ float bs[256];
  int tid = threadIdx.x;
  for (int i = tid; i < 2560; i += 256) ws[i] = W[i];
  bs[tid] = b[tid];
  __syncthreads();
  int row0 = blockIdx.x * 32;
  for (int rr = 0; rr < 32; ++rr) {
    int row = row0 + rr;
    if (row >= n) break;
    float acc = bs[tid];
#pragma unroll
    for (int i = 0; i < 10; ++i) acc += x[row * 10 + i] * ws[i * 256 + tid];
    hbf[(size_t)row * 256 + tid] = f2bf(fmaxf(acc, 0.f));
  }
}

// ---------------------------------------------------------------------------
// QKV GEMM (R10-frozen core, exact R0 form — 128x64 tile, grid 12x391;
// R2's 128x128 and R6's A-resident variants both regressed: these GEMMs
// are occupancy-limited, not traffic-limited). Dual-dtype epilogue:
// cols [0,256) -> bf16 Qbf; cols [256,768) -> fp8 KV8.
// ---------------------------------------------------------------------------
__global__ __launch_bounds__(256) void gemm_qkv_k(
    const ushort_t* __restrict__ A1, const ushort_t* __restrict__ BT,
    ushort_t* __restrict__ Qbf, u8* __restrict__ KV8, int M) {
  const int K1 = 256, Ktot = 256;
  __shared__ __align__(16) ushort_t Als[128 * 64];
  __shared__ __align__(16) ushort_t Bls[64 * 64];
  int tid = threadIdx.x;
  int lane = tid & 63, w = tid >> 6;
  int quad = lane >> 4, m = lane & 15;
  int row0 = blockIdx.y * 128, col0 = blockIdx.x * 64;
  float4v acc[2][4];
#pragma unroll
  for (int t = 0; t < 2; ++t)
#pragma unroll
    for (int j = 0; j < 4; ++j) acc[t][j] = (float4v){0.f, 0.f, 0.f, 0.f};

  int srow = tid >> 3;
  int skc = (tid & 7) * 8;
  char* alsb = (char*)Als + w * 1024;
  char* blsb = (char*)Bls + w * 1024;

  for (int k0 = 0; k0 < Ktot; k0 += 64) {
#pragma unroll
    for (int q = 0; q < 4; ++q) {
      int r = row0 + q * 32 + srow;
      if (r < M) {
        const ushort_t* g = A1 + (size_t)r * K1 + k0 + skc;
        __builtin_amdgcn_global_load_lds((gas_p)g, (las_p)(alsb + q * 4096),
                                         16, 0, 0);
      }
    }
#pragma unroll
    for (int q = 0; q < 2; ++q) {
      const ushort_t* g = BT + (size_t)(col0 + q * 32 + srow) * Ktot + k0 + skc;
      __builtin_amdgcn_global_load_lds((gas_p)g, (las_p)(blsb + q * 4096), 16,
                                       0, 0);
    }
    __syncthreads();
#pragma unroll
    for (int ks = 0; ks < 64; ks += 32) {
      short8 a0 = *(const short8*)&Als[(w * 32 + m) * 64 + ks + quad * 8];
      short8 a1 = *(const short8*)&Als[(w * 32 + 16 + m) * 64 + ks + quad * 8];
#pragma unroll
      for (int j = 0; j < 4; ++j) {
        short8 bj = *(const short8*)&Bls[(16 * j + m) * 64 + ks + quad * 8];
        acc[0][j] =
            __builtin_amdgcn_mfma_f32_16x16x32_bf16(a0, bj, acc[0][j], 0, 0, 0);
        acc[1][j] =
            __builtin_amdgcn_mfma_f32_16x16x32_bf16(a1, bj, acc[1][j], 0, 0, 0);
      }
    }
    __syncthreads();
  }

#pragma unroll
  for (int t = 0; t < 2; ++t) {
#pragma unroll
    for (int j = 0; j < 4; ++j) {
      int col = col0 + 16 * j + m;
#pragma unroll
      for (int rr = 0; rr < 4; ++rr) {
        int row = row0 + w * 32 + 16 * t + quad * 4 + rr;
        if (row >= M) continue;
        float v = acc[t][j][rr];
        if (col < 256)
          Qbf[(size_t)row * 256 + col] = f2bf(v);
        else
          KV8[(size_t)row * 512 + (col - 256)] = f2f8(v);
      }
    }
  }
}

// ---------------------------------------------------------------------------
// Wm GEMM + residual + LayerNorm FUSED (R14-proven), 64x256 tile, K=512.
// ---------------------------------------------------------------------------
__global__ __launch_bounds__(256) void gemm_ln_k(
    ushort_t* __restrict__ hbf, const ushort_t* __restrict__ aggbf,
    const ushort_t* __restrict__ BT, const float* __restrict__ bcomb,
    const float* __restrict__ gamma, const float* __restrict__ beta, int M) {
  __shared__ __align__(16) ushort_t Als[64 * 64];   // 8 KB
  __shared__ __align__(16) ushort_t Bls[256 * 64];  // 32 KB
  int tid = threadIdx.x;
  int lane = tid & 63, w = tid >> 6;
  int quad = lane >> 4, m = lane & 15;
  int row0 = blockIdx.x * 64;
  float4v acc[16];
#pragma unroll
  for (int j = 0; j < 16; ++j) acc[j] = (float4v){0.f, 0.f, 0.f, 0.f};

  int srow = tid >> 3;
  int skc = (tid & 7) * 8;
  char* alsb = (char*)Als + w * 1024;
  char* blsb = (char*)Bls + w * 1024;

  for (int k0 = 0; k0 < 512; k0 += 64) {
    const ushort_t* Ap = (k0 < 256) ? (const ushort_t*)hbf : aggbf;
    int kk = k0 & 255;
#pragma unroll
    for (int q = 0; q < 2; ++q) {
      int r = row0 + q * 32 + srow;
      if (r < M) {
        const ushort_t* g = Ap + (size_t)r * 256 + kk + skc;
        __builtin_amdgcn_global_load_lds((gas_p)g, (las_p)(alsb + q * 4096),
                                         16, 0, 0);
      }
    }
#pragma unroll
    for (int q = 0; q < 8; ++q) {
      const ushort_t* g = BT + (size_t)(q * 32 + srow) * 512 + k0 + skc;
      __builtin_amdgcn_global_load_lds((gas_p)g, (las_p)(blsb + q * 4096), 16,
                                       0, 0);
    }
    __syncthreads();
#pragma unroll
    for (int ks = 0; ks < 64; ks += 32) {
      short8 a = *(const short8*)&Als[(w * 16 + m) * 64 + ks + quad * 8];
#pragma unroll
      for (int j = 0; j < 16; ++j) {
        short8 bj = *(const short8*)&Bls[(16 * j + m) * 64 + ks + quad * 8];
        acc[j] = __builtin_amdgcn_mfma_f32_16x16x32_bf16(a, bj, acc[j], 0, 0, 0);
      }
    }
    __syncthreads();
  }

#pragma unroll
  for (int rr = 0; rr < 4; ++rr) {
    int row = row0 + w * 16 + quad * 4 + rr;
    if (row >= M) continue;
    float sv[16];
    float sum = 0.f, sq = 0.f;
#pragma unroll
    for (int j = 0; j < 16; ++j) {
      int col = m + 16 * j;
      float u = fmaxf(acc[j][rr] + bcomb[col], 0.f);
      float s = bf2f(hbf[(size_t)row * 256 + col]) + u;
      sv[j] = s;
      sum += s;
      sq += s * s;
    }
#pragma unroll
    for (int off = 1; off < 16; off <<= 1) {
      sum += __shfl_xor(sum, off);
      sq += __shfl_xor(sq, off);
    }
    float mean = sum * (1.f / 256.f);
    float var = sq * (1.f / 256.f) - mean * mean;
    float r = rsqrtf(var + 1e-5f);
#pragma unroll
    for (int j = 0; j < 16; ++j) {
      int col = m + 16 * j;
      float o = (sv[j] - mean) * r * gamma[col] + beta[col];
      hbf[(size_t)row * 256 + col] = f2bf(o);
    }
  }
}

// ---------------------------------------------------------------------------
// Output head FUSED (R15-proven)
// ---------------------------------------------------------------------------
__global__ __launch_bounds__(256) void head_fused_k(
    const ushort_t* __restrict__ hbf, const ushort_t* __restrict__ W1T,
    const float* __restrict__ b1, const float* __restrict__ W2,
    const float* __restrict__ b2, float* __restrict__ out, int M) {
  __shared__ __align__(16) ushort_t Als[64 * 64];
  __shared__ __align__(16) ushort_t Bls[128 * 64];
  int tid = threadIdx.x;
  int lane = tid & 63, w = tid >> 6;
  int quad = lane >> 4, m = lane & 15;
  int row0 = blockIdx.x * 64;
  float4v acc[8];
#pragma unroll
  for (int j = 0; j < 8; ++j) acc[j] = (float4v){0.f, 0.f, 0.f, 0.f};

  int srow = tid >> 3;
  int skc = (tid & 7) * 8;
  char* alsb = (char*)Als + w * 1024;
  char* blsb = (char*)Bls + w * 1024;

  for (int k0 = 0; k0 < 256; k0 += 64) {
#pragma unroll
    for (int q = 0; q < 2; ++q) {
      int r = row0 + q * 32 + srow;
      if (r < M) {
        const ushort_t* g = hbf + (size_t)r * 256 + k0 + skc;
        __builtin_amdgcn_global_load_lds((gas_p)g, (las_p)(alsb + q * 4096),
                                         16, 0, 0);
      }
    }
#pragma unroll
    for (int q = 0; q < 4; ++q) {
      const ushort_t* g = W1T + (size_t)(q * 32 + srow) * 256 + k0 + skc;
      __builtin_amdgcn_global_load_lds((gas_p)g, (las_p)(blsb + q * 4096), 16,
                                       0, 0);
    }
    __syncthreads();
#pragma unroll
    for (int ks = 0; ks < 64; ks += 32) {
      short8 a = *(const short8*)&Als[(w * 16 + m) * 64 + ks + quad * 8];
#pragma unroll
      for (int j = 0; j < 8; ++j) {
        short8 bj = *(const short8*)&Bls[(16 * j + m) * 64 + ks + quad * 8];
        acc[j] = __builtin_amdgcn_mfma_f32_16x16x32_bf16(a, bj, acc[j], 0, 0, 0);
      }
    }
    __syncthreads();
  }

#pragma unroll
  for (int rr = 0; rr < 4; ++rr) {
    int row = row0 + w * 16 + quad * 4 + rr;
    if (row >= M) continue;
    float p = 0.f;
#pragma unroll
    for (int j = 0; j < 8; ++j) {
      int col = m + 16 * j;
      float t = fmaxf(acc[j][rr] + b1[col], 0.f);
      p += t * W2[col];
    }
#pragma unroll
    for (int off = 1; off < 16; off <<= 1) p += __shfl_xor(p, off);
    if (m == 0) out[row] = p + b2[0];
  }
}

// ---------------------------------------------------------------------------
// FUSED edge phase (R0 loop structure — proven fastest). fp8 K/V gathers,
// NO online max (softmax shift-invariance). v7: edge features travel INSIDE
// the 16-B CSR record (bf16-packed at fill time), eliminating the random
// 64-B-line pulls at ea[er.y*3] that were ~40-50 MB of the 244 MB FETCH.
// The kernel is fetch-throughput-bound (~11 B/cyc/CU = the measured HBM-
// bound per-CU rate), so time scales with bytes.
// Degree-0: loop skipped -> l=0 -> clip(1e-12) -> agg=0, as the reference.
// ---------------------------------------------------------------------------
__global__ __launch_bounds__(256) void node_fused_k(
    const ushort_t* __restrict__ Q, const u8* __restrict__ KV8,
    const float* __restrict__ We_l, const int* __restrict__ rowptr,
    const int4* __restrict__ erec, ushort_t* __restrict__ agg, int n) {
  int node = (blockIdx.x * blockDim.x + threadIdx.x) >> 6;
  if (node >= n) return;
  int lane = threadIdx.x & 63;
  int hl = lane & 31;
  int slot = lane >> 5;
  ushort8v qu = *((const ushort8v*)(Q + (size_t)node * 256) + hl);
  float q[8];
#pragma unroll
  for (int i = 0; i < 8; ++i) q[i] = bf2f(qu[i]);
  int start = rowptr[node], end = rowptr[node + 1];
  int hh = hl >> 2;
  float w0 = We_l[0 * 8 + hh], w1 = We_l[1 * 8 + hh], w2 = We_l[2 * 8 + hh];
  float l = 0.f;
  float acc[8];
#pragma unroll
  for (int i = 0; i < 8; ++i) acc[i] = 0.f;

  int iters = (end - start + 1) >> 1;
  for (int it = 0; it < iters; ++it) {
    int p = start + 2 * it + slot;
    if (p < end) {
      int4 er = erec[p];
      const u8* base = KV8 + (size_t)er.x * 512;
      uint2 ku = *((const uint2*)base + hl);
      uint2 vu = *((const uint2*)(base + 256) + hl);
      float kf[8], vf[8];
      f8x4_to_f32(ku.x, kf);
      f8x4_to_f32(ku.y, kf + 4);
      f8x4_to_f32(vu.x, vf);
      f8x4_to_f32(vu.y, vf + 4);
      float d = 0.f;
#pragma unroll
      for (int i = 0; i < 8; ++i) d += q[i] * kf[i];
      d += __shfl_xor(d, 1);
      d += __shfl_xor(d, 2);
      float e0 = bf2f((ushort_t)((u32)er.y & 0xFFFF));
      float e1 = bf2f((ushort_t)((u32)er.y >> 16));
      float e2 = bf2f((ushort_t)((u32)er.z & 0xFFFF));
      float bias = e0 * w0 + e1 * w1 + e2 * w2;
      float a = d * 0.17677669529663687f + bias;  // 1/sqrt(32)
      a = (a > 0.f) ? a : 0.2f * a;               // leaky_relu 0.2
      float wv = __expf(a);
      l += wv;
#pragma unroll
      for (int i = 0; i < 8; ++i) acc[i] += vf[i] * wv;
    }
  }
  // merge the two half-wave partial sums
  l += __shfl_xor(l, 32);
  float inv = 1.f / fmaxf(l, 1e-12f);
  ushort8v o;
#pragma unroll
  for (int i = 0; i < 8; ++i) {
    float v = (acc[i] + __shfl_xor(acc[i], 32)) * inv;
    o[i] = f2bf(v);
  }
  if (slot == 0)
    *((ushort8v*)(agg + (size_t)node * 256) + hl) = o;
}

// ---------------------------------------------------------------------------
extern "C" void kernel_launch(void* const* d_in, const int* in_sizes, int n_in,
                              void* d_out, int out_size, void* d_ws,
                              size_t ws_size, hipStream_t stream) {
  const float* x = (const float*)d_in[0];
  const float* edge_attr = (const float*)d_in[1];
  const float* W_in = (const float*)d_in[2];
  const float* b_in = (const float*)d_in[3];
  const float* Wq = (const float*)d_in[4];
  const float* Wk = (const float*)d_in[5];
  const float* Wv = (const float*)d_in[6];
  const float* We = (const float*)d_in[7];
  const float* Wo = (const float*)d_in[8];
  const float* bo = (const float*)d_in[9];
  const float* Wm = (const float*)d_in[10];
  const float* bm = (const float*)d_in[11];
  const float* gamma = (const float*)d_in[12];
  const float* beta = (const float*)d_in[13];
  const float* W_h1 = (const float*)d_in[14];
  const float* b_h1 = (const float*)d_in[15];
  const float* W_h2 = (const float*)d_in[16];
  const float* b_h2 = (const float*)d_in[17];
  const u32* eidx_w = (const u32*)d_in[18];

  // ws layout (~118 MB)
  float* ws = (float*)d_ws;
  const size_t NH_ = (size_t)N_NODES * HDIM;
  ushort_t* hbf = (ushort_t*)ws;            // N x 256 bf16, persists
  ushort_t* Qbf = hbf + NH_;                // N x 256 bf16
  u8* KV8 = (u8*)(Qbf + NH_);               // N x 512 fp8 (K | V)
  ushort_t* aggbf = (ushort_t*)(KV8 + (size_t)N_NODES * 512);  // N x 256
  int* idxflag = (int*)(aggbf + NH_);
  int4* erec = (int4*)(idxflag + 4);        // E packed 16-B records
  int* rowptr = (int*)(erec + E_EDGES);     // N+1
  int* dcnt = rowptr + N_NODES + 1;         // N (hist)
  int* cursor = dcnt + N_NODES;             // N (fill) — zeroed together
  int* scanned = cursor + N_NODES;          // N
  int* bsum = scanned + N_NODES;            // 256
  float* bcomb = (float*)(bsum + 256);      // 3 x 256 fp32
  ushort_t* WT = (ushort_t*)(bcomb + 3 * 256);
  const size_t W64K = (size_t)HDIM * HDIM;
  const size_t W128K = (size_t)2 * HDIM * HDIM;
  ushort_t* WqkvT = WT;                     // 3 layers x (768 x 256)
  ushort_t* WmT = WqkvT + 3 * 3 * W64K;     // 3 layers x (256 x 512)
  ushort_t* Wh1T = WmT + 3 * W128K;
  // transient: consumed by fill_k before the first QKV gemm writes Qbf
  int* srcI = (int*)Qbf;
  int* dstI = srcI + E_EDGES;

  detect_idx_k<<<1, 256, 0, stream>>>(eidx_w, idxflag);
  hipMemsetAsync(dcnt, 0, (size_t)2 * N_NODES * sizeof(int), stream);
  convert_hist_k<<<(E_EDGES + 255) / 256, 256, 0, stream>>>(
      eidx_w, idxflag, srcI, dstI, dcnt, E_EDGES);
  const int nsb = (N_NODES + 255) / 256;
  scan1_k<<<nsb, 256, 0, stream>>>(dcnt, scanned, bsum, N_NODES);
  scan2_k<<<1, 256, 0, stream>>>(bsum, nsb);
  scan3_k<<<nsb, 256, 0, stream>>>(scanned, bsum, rowptr, N_NODES);
  fill_k<<<(E_EDGES + 255) / 256, 256, 0, stream>>>(
      srcI, dstI, edge_attr, rowptr, cursor, erec, E_EDGES);

  wtrans_all_k<<<dim3(32, 4, 13), 256, 0, stream>>>(Wq, Wk, Wv, Wm, W_h1,
                                                    WqkvT, WmT, Wh1T);
  wcomb_k<<<dim3(4, 4, 3), 256, 0, stream>>>(Wo, Wm, WmT);
  bcomb_k<<<dim3(1, 1, 3), 256, 0, stream>>>(bo, bm, Wm, bcomb);

  input_proj_k<<<(N_NODES + 31) / 32, 256, 0, stream>>>(x, W_in, b_in, hbf,
                                                        N_NODES);
  dim3 gqkv(768 / 64, (N_NODES + 127) / 128);  // (12, 391)
  const int gml = (N_NODES + 63) / 64;         // 782
  const int nodewave_grid = (N_NODES * 64 + 255) / 256;

  for (int l = 0; l < NLAYERS; ++l) {
    const float* We_l = We + (size_t)l * EDGED * NHEADS;

    // QKV = hbf @ [Wq|Wk|Wv] -> Q bf16, K/V fp8
    gemm_qkv_k<<<gqkv, 256, 0, stream>>>(
        hbf, WqkvT + (size_t)l * 3 * W64K, Qbf, KV8, N_NODES);
    // fused attention + softmax + aggregation (fp8 K/V, ea-in-record)
    node_fused_k<<<nodewave_grid, 256, 0, stream>>>(
        Qbf, KV8, We_l, rowptr, erec, aggbf, N_NODES);
    // hbf = LN(hbf + relu([hbf|agg]@Wm' + bcomb)) — GEMM+LN fused, in-place
    gemm_ln_k<<<gml, 256, 0, stream>>>(
        hbf, aggbf, WmT + (size_t)l * W128K, bcomb + l * 256,
        gamma + (size_t)l * HDIM, beta + (size_t)l * HDIM, N_NODES);
  }
  // fused output head
  head_fused_k<<<gml, 256, 0, stream>>>(hbf, Wh1T, b_h1, W_h2, b_h2,
                                        (float*)d_out, N_NODES);
}

// Round 9
// 756.824 us; speedup vs baseline: 1.0969x; 1.0020x over previous
//
#include <hip/hip_runtime.h>
#include <math.h>

#define N_NODES 50000
#define E_EDGES 800000
#define HDIM 256
#define NHEADS 8
#define HEADD 32
#define EDGED 3
#define NLAYERS 3

typedef unsigned int u32;
typedef unsigned char u8;
typedef unsigned short ushort_t;
typedef __attribute__((ext_vector_type(8))) short short8;
typedef __attribute__((ext_vector_type(8))) unsigned short ushort8v;
typedef __attribute__((ext_vector_type(4))) float float4v;
typedef __attribute__((ext_vector_type(2))) float float2v;

typedef __attribute__((address_space(1))) const void* gas_p;
typedef __attribute__((address_space(3))) void* las_p;

__device__ __forceinline__ float bf2f(ushort_t u) {
  union { u32 i; float f; } v;
  v.i = ((u32)u) << 16;
  return v.f;
}
// fp32 -> bf16 RNE
__device__ __forceinline__ ushort_t f2bf(float f) {
  u32 u = __float_as_uint(f);
  u = (u + 0x7FFF + ((u >> 16) & 1)) >> 16;
  return (ushort_t)u;
}
// fp32 -> fp8 e4m3 (HW convert)
__device__ __forceinline__ u8 f2f8(float f) {
  int p = __builtin_amdgcn_cvt_pk_fp8_f32(f, 0.f, 0, false);
  return (u8)(p & 0xFF);
}
// 4x fp8 e4m3 -> fp32 (HW convert; builtin returns ext-vector float2)
__device__ __forceinline__ void f8x4_to_f32(u32 v, float* out) {
  float2v a = __builtin_amdgcn_cvt_pk_f32_fp8((int)v, false);
  float2v b = __builtin_amdgcn_cvt_pk_f32_fp8((int)v, true);
  out[0] = a[0];
  out[1] = a[1];
  out[2] = b[0];
  out[3] = b[1];
}

// ---------------------------------------------------------------------------
// edge_index layout detection (int64 vs int32 staging)
// ---------------------------------------------------------------------------
__global__ __launch_bounds__(256) void detect_idx_k(const u32* __restrict__ w,
                                                    int* __restrict__ flag) {
  __shared__ u32 sm[256];
  u32 mx = 0;
  for (int k = threadIdx.x; k < 4096; k += 256) mx = max(mx, w[2 * k + 1]);
  sm[threadIdx.x] = mx;
  __syncthreads();
  for (int s = 128; s > 0; s >>= 1) {
    if (threadIdx.x < s)
      sm[threadIdx.x] = max(sm[threadIdx.x], sm[threadIdx.x + s]);
    __syncthreads();
  }
  if (threadIdx.x == 0) flag[0] = (sm[0] == 0) ? 1 : 0;
}

// convert + dst histogram fused
__global__ __launch_bounds__(256) void convert_hist_k(
    const u32* __restrict__ w, const int* __restrict__ flag,
    int* __restrict__ src32, int* __restrict__ dst32, int* __restrict__ dcnt,
    int E_) {
  int e = blockIdx.x * blockDim.x + threadIdx.x;
  if (e >= E_) return;
  int s, d;
  if (flag[0]) {
    s = (int)w[2 * e];
    d = (int)w[2 * (E_ + e)];
  } else {
    s = (int)w[e];
    d = (int)w[E_ + e];
  }
  src32[e] = s;
  dst32[e] = d;
  atomicAdd(&dcnt[d], 1);
}

__global__ __launch_bounds__(256) void scan1_k(const int* __restrict__ deg,
                                               int* __restrict__ scanned,
                                               int* __restrict__ bsum, int n) {
  __shared__ int tmp[256];
  int tid = threadIdx.x;
  int i = blockIdx.x * 256 + tid;
  tmp[tid] = (i < n) ? deg[i] : 0;
  __syncthreads();
  for (int off = 1; off < 256; off <<= 1) {
    int t = (tid >= off) ? tmp[tid - off] : 0;
    __syncthreads();
    tmp[tid] += t;
    __syncthreads();
  }
  if (i < n) scanned[i] = tmp[tid];
  if (tid == 255) bsum[blockIdx.x] = tmp[255];
}

__global__ __launch_bounds__(256) void scan2_k(int* __restrict__ bsum, int nb) {
  __shared__ int tmp[256];
  int tid = threadIdx.x;
  tmp[tid] = (tid < nb) ? bsum[tid] : 0;
  __syncthreads();
  for (int off = 1; off < 256; off <<= 1) {
    int t = (tid >= off) ? tmp[tid - off] : 0;
    __syncthreads();
    tmp[tid] += t;
    __syncthreads();
  }
  if (tid < nb) bsum[tid] = tmp[tid];
}

__global__ __launch_bounds__(256) void scan3_k(const int* __restrict__ scanned,
                                               const int* __restrict__ bsum,
                                               int* __restrict__ rowptr, int n) {
  int i = blockIdx.x * 256 + threadIdx.x;
  if (i < n)
    rowptr[i + 1] = scanned[i] + (blockIdx.x > 0 ? bsum[blockIdx.x - 1] : 0);
  if (i == 0) rowptr[0] = 0;
}

// CSR fill with packed 16-B records: {src, ea0|ea1 (bf16), ea2 (bf16), 0}.
// Embedding the edge features kills node_fused's random 64-B-line pulls at
// ea[er.y*3] (R8-proven: FETCH 244.6 -> 194.7 MB, 86 -> 76 us).
__global__ __launch_bounds__(256) void fill_k(
    const int* __restrict__ srcI, const int* __restrict__ dstI,
    const float* __restrict__ ea, const int* __restrict__ rowptr,
    int* __restrict__ cursor, int4* __restrict__ erec, int E_) {
  int e = blockIdx.x * blockDim.x + threadIdx.x;
  if (e >= E_) return;
  int d = dstI[e];
  int p = rowptr[d] + atomicAdd(&cursor[d], 1);
  float a0 = ea[3 * (size_t)e + 0];
  float a1 = ea[3 * (size_t)e + 1];
  float a2 = ea[3 * (size_t)e + 2];
  int4 r;
  r.x = srcI[e];
  r.y = (int)((u32)f2bf(a0) | ((u32)f2bf(a1) << 16));
  r.z = (int)(u32)f2bf(a2);
  r.w = 0;
  erec[p] = r;
}

// ---------------------------------------------------------------------------
// ALL weight transposes in one launch (R15-proven, exact R0 form).
// ---------------------------------------------------------------------------
__global__ __launch_bounds__(256) void wtrans_all_k(
    const float* __restrict__ Wq, const float* __restrict__ Wk,
    const float* __restrict__ Wv, const float* __restrict__ Wm,
    const float* __restrict__ Wh1, ushort_t* __restrict__ WqkvT,
    ushort_t* __restrict__ WmT, ushort_t* __restrict__ Wh1T) {
  int z = blockIdx.z;
  const float* W;
  ushort_t* WT;
  int K, N;
  if (z < 9) {
    if (blockIdx.x >= 16) return;
    int l = z / 3, m = z % 3;
    W = (m == 0 ? Wq : m == 1 ? Wk : Wv) + (size_t)l * 65536;
    WT = WqkvT + ((size_t)l * 3 + m) * 65536;
    K = 256;
    N = 256;
  } else if (z < 12) {
    int l = z - 9;
    W = Wm + (size_t)l * 131072;
    WT = WmT + (size_t)l * 131072;
    K = 512;
    N = 256;
  } else {
    if (blockIdx.x >= 16 || blockIdx.y >= 2) return;
    W = Wh1;
    WT = Wh1T;
    K = 256;
    N = 128;
  }
  __shared__ float t[64][17];
  int k0 = blockIdx.x * 16, n0 = blockIdx.y * 64;
  int tid = threadIdx.x;
  int r = tid >> 6, c = tid & 63;
#pragma unroll
  for (int i = 0; i < 4; ++i)
    t[c][r + 4 * i] = W[(size_t)(k0 + r + 4 * i) * N + n0 + c];
  __syncthreads();
  int n = tid >> 2, j4 = (tid & 3) * 4;
  ushort4 o;
  o.x = f2bf(t[n][j4 + 0]);
  o.y = f2bf(t[n][j4 + 1]);
  o.z = f2bf(t[n][j4 + 2]);
  o.w = f2bf(t[n][j4 + 3]);
  *(ushort4*)&WT[(size_t)(n0 + n) * K + k0 + j4] = o;
}

// ---------------------------------------------------------------------------
// Wo->Wm folding (R12-proven, exact R0 form)
// ---------------------------------------------------------------------------
__global__ __launch_bounds__(256) void wcomb_k(const float* __restrict__ Wo,
                                               const float* __restrict__ Wm,
                                               ushort_t* __restrict__ WmT) {
  int l = blockIdx.z;
  const float* A = Wo + (size_t)l * 65536;
  const float* B = Wm + (size_t)l * 131072 + 65536;
  ushort_t* Out = WmT + (size_t)l * 131072;
  __shared__ float As[16][64];
  __shared__ float Bs[16][64];
  int tid = threadIdx.x;
  int tx = tid & 15, ty = tid >> 4;
  int k0 = blockIdx.x * 64, n0 = blockIdx.y * 64;
  float acc[4][4] = {};
  int arow = tid >> 2;
  int aj = (tid & 3) * 4;
  int brow = tid >> 4;
  int bcol = (tid & 15) * 4;
  for (int j0 = 0; j0 < 256; j0 += 16) {
    float4 av = *(const float4*)(A + (size_t)(k0 + arow) * 256 + j0 + aj);
    As[aj + 0][arow] = av.x;
    As[aj + 1][arow] = av.y;
    As[aj + 2][arow] = av.z;
    As[aj + 3][arow] = av.w;
    *(float4*)&Bs[brow][bcol] =
        *(const float4*)(B + (size_t)(j0 + brow) * 256 + n0 + bcol);
    __syncthreads();
#pragma unroll
    for (int j = 0; j < 16; ++j) {
      float a[4], bb[4];
#pragma unroll
      for (int i = 0; i < 4; ++i) a[i] = As[j][ty * 4 + i];
#pragma unroll
      for (int jj = 0; jj < 4; ++jj) bb[jj] = Bs[j][tx * 4 + jj];
#pragma unroll
      for (int i = 0; i < 4; ++i)
#pragma unroll
        for (int jj = 0; jj < 4; ++jj) acc[i][jj] += a[i] * bb[jj];
    }
    __syncthreads();
  }
#pragma unroll
  for (int i = 0; i < 4; ++i)
#pragma unroll
    for (int jj = 0; jj < 4; ++jj) {
      int k = k0 + ty * 4 + i, n = n0 + tx * 4 + jj;
      Out[(size_t)n * 512 + 256 + k] = f2bf(acc[i][jj]);
    }
}

// bcomb[l][n] = bm[l][n] + sum_j bo[l][j] * Wm[l][256+j][n]
__global__ __launch_bounds__(256) void bcomb_k(const float* __restrict__ bo,
                                               const float* __restrict__ bm,
                                               const float* __restrict__ Wm,
                                               float* __restrict__ bcomb) {
  int l = blockIdx.z;
  int n = threadIdx.x;
  const float* Bw = Wm + (size_t)l * 131072 + 65536;
  const float* bol = bo + l * 256;
  float acc = bm[l * 256 + n];
  for (int j = 0; j < 256; ++j) acc += bol[j] * Bw[(size_t)j * 256 + n];
  bcomb[l * 256 + n] = acc;
}

// ---------------------------------------------------------------------------
// Input projection: hbf = bf16(relu(x @ W_in + b_in))
// ---------------------------------------------------------------------------
__global__ __launch_bounds__(256) void input_proj_k(
    const float* __restrict__ x, const float* __restrict__ W,
    const float* __restrict__ b, ushort_t* __restrict__ hbf, int n) {
  __shared__ float ws[10 * 256];
  __shared__ float bs[256];
  int tid = threadIdx.x;
  for (int i = tid; i < 2560; i += 256) ws[i] = W[i];
  bs[tid] = b[tid];
  __syncthreads();
  int row0 = blockIdx.x * 32;
  for (int rr = 0; rr < 32; ++rr) {
    int row = row0 + rr;
    if (row >= n) break;
    float acc = bs[tid];
#pragma unroll
    for (int i = 0; i < 10; ++i) acc += x[row * 10 + i] * ws[i * 256 + tid];
    hbf[(size_t)row * 256 + tid] = f2bf(fmaxf(acc, 0.f));
  }
}

// ---------------------------------------------------------------------------
// QKV GEMM (R10-frozen core, exact R0 form — 128x64 tile, grid 12x391;
// R2's 128x128 and R6's A-resident variants both regressed: these GEMMs
// are occupancy-limited, not traffic-limited). Dual-dtype epilogue:
// cols [0,256) -> bf16 Qbf; cols [256,768) -> fp8 KV8.
// ---------------------------------------------------------------------------
__global__ __launch_bounds__(256) void gemm_qkv_k(
    const ushort_t* __restrict__ A1, const ushort_t* __restrict__ BT,
    ushort_t* __restrict__ Qbf, u8* __restrict__ KV8, int M) {
  const int K1 = 256, Ktot = 256;
  __shared__ __align__(16) ushort_t Als[128 * 64];
  __shared__ __align__(16) ushort_t Bls[64 * 64];
  int tid = threadIdx.x;
  int lane = tid & 63, w = tid >> 6;
  int quad = lane >> 4, m = lane & 15;
  int row0 = blockIdx.y * 128, col0 = blockIdx.x * 64;
  float4v acc[2][4];
#pragma unroll
  for (int t = 0; t < 2; ++t)
#pragma unroll
    for (int j = 0; j < 4; ++j) acc[t][j] = (float4v){0.f, 0.f, 0.f, 0.f};

  int srow = tid >> 3;
  int skc = (tid & 7) * 8;
  char* alsb = (char*)Als + w * 1024;
  char* blsb = (char*)Bls + w * 1024;

  for (int k0 = 0; k0 < Ktot; k0 += 64) {
#pragma unroll
    for (int q = 0; q < 4; ++q) {
      int r = row0 + q * 32 + srow;
      if (r < M) {
        const ushort_t* g = A1 + (size_t)r * K1 + k0 + skc;
        __builtin_amdgcn_global_load_lds((gas_p)g, (las_p)(alsb + q * 4096),
                                         16, 0, 0);
      }
    }
#pragma unroll
    for (int q = 0; q < 2; ++q) {
      const ushort_t* g = BT + (size_t)(col0 + q * 32 + srow) * Ktot + k0 + skc;
      __builtin_amdgcn_global_load_lds((gas_p)g, (las_p)(blsb + q * 4096), 16,
                                       0, 0);
    }
    __syncthreads();
#pragma unroll
    for (int ks = 0; ks < 64; ks += 32) {
      short8 a0 = *(const short8*)&Als[(w * 32 + m) * 64 + ks + quad * 8];
      short8 a1 = *(const short8*)&Als[(w * 32 + 16 + m) * 64 + ks + quad * 8];
#pragma unroll
      for (int j = 0; j < 4; ++j) {
        short8 bj = *(const short8*)&Bls[(16 * j + m) * 64 + ks + quad * 8];
        acc[0][j] =
            __builtin_amdgcn_mfma_f32_16x16x32_bf16(a0, bj, acc[0][j], 0, 0, 0);
        acc[1][j] =
            __builtin_amdgcn_mfma_f32_16x16x32_bf16(a1, bj, acc[1][j], 0, 0, 0);
      }
    }
    __syncthreads();
  }

#pragma unroll
  for (int t = 0; t < 2; ++t) {
#pragma unroll
    for (int j = 0; j < 4; ++j) {
      int col = col0 + 16 * j + m;
#pragma unroll
      for (int rr = 0; rr < 4; ++rr) {
        int row = row0 + w * 32 + 16 * t + quad * 4 + rr;
        if (row >= M) continue;
        float v = acc[t][j][rr];
        if (col < 256)
          Qbf[(size_t)row * 256 + col] = f2bf(v);
        else
          KV8[(size_t)row * 512 + (col - 256)] = f2f8(v);
      }
    }
  }
}

// ---------------------------------------------------------------------------
// Wm GEMM + residual + LayerNorm FUSED (R14-proven), 64x256 tile, K=512.
// ---------------------------------------------------------------------------
__global__ __launch_bounds__(256) void gemm_ln_k(
    ushort_t* __restrict__ hbf, const ushort_t* __restrict__ aggbf,
    const ushort_t* __restrict__ BT, const float* __restrict__ bcomb,
    const float* __restrict__ gamma, const float* __restrict__ beta, int M) {
  __shared__ __align__(16) ushort_t Als[64 * 64];   // 8 KB
  __shared__ __align__(16) ushort_t Bls[256 * 64];  // 32 KB
  int tid = threadIdx.x;
  int lane = tid & 63, w = tid >> 6;
  int quad = lane >> 4, m = lane & 15;
  int row0 = blockIdx.x * 64;
  float4v acc[16];
#pragma unroll
  for (int j = 0; j < 16; ++j) acc[j] = (float4v){0.f, 0.f, 0.f, 0.f};

  int srow = tid >> 3;
  int skc = (tid & 7) * 8;
  char* alsb = (char*)Als + w * 1024;
  char* blsb = (char*)Bls + w * 1024;

  for (int k0 = 0; k0 < 512; k0 += 64) {
    const ushort_t* Ap = (k0 < 256) ? (const ushort_t*)hbf : aggbf;
    int kk = k0 & 255;
#pragma unroll
    for (int q = 0; q < 2; ++q) {
      int r = row0 + q * 32 + srow;
      if (r < M) {
        const ushort_t* g = Ap + (size_t)r * 256 + kk + skc;
        __builtin_amdgcn_global_load_lds((gas_p)g, (las_p)(alsb + q * 4096),
                                         16, 0, 0);
      }
    }
#pragma unroll
    for (int q = 0; q < 8; ++q) {
      const ushort_t* g = BT + (size_t)(q * 32 + srow) * 512 + k0 + skc;
      __builtin_amdgcn_global_load_lds((gas_p)g, (las_p)(blsb + q * 4096), 16,
                                       0, 0);
    }
    __syncthreads();
#pragma unroll
    for (int ks = 0; ks < 64; ks += 32) {
      short8 a = *(const short8*)&Als[(w * 16 + m) * 64 + ks + quad * 8];
#pragma unroll
      for (int j = 0; j < 16; ++j) {
        short8 bj = *(const short8*)&Bls[(16 * j + m) * 64 + ks + quad * 8];
        acc[j] = __builtin_amdgcn_mfma_f32_16x16x32_bf16(a, bj, acc[j], 0, 0, 0);
      }
    }
    __syncthreads();
  }

#pragma unroll
  for (int rr = 0; rr < 4; ++rr) {
    int row = row0 + w * 16 + quad * 4 + rr;
    if (row >= M) continue;
    float sv[16];
    float sum = 0.f, sq = 0.f;
#pragma unroll
    for (int j = 0; j < 16; ++j) {
      int col = m + 16 * j;
      float u = fmaxf(acc[j][rr] + bcomb[col], 0.f);
      float s = bf2f(hbf[(size_t)row * 256 + col]) + u;
      sv[j] = s;
      sum += s;
      sq += s * s;
    }
#pragma unroll
    for (int off = 1; off < 16; off <<= 1) {
      sum += __shfl_xor(sum, off);
      sq += __shfl_xor(sq, off);
    }
    float mean = sum * (1.f / 256.f);
    float var = sq * (1.f / 256.f) - mean * mean;
    float r = rsqrtf(var + 1e-5f);
#pragma unroll
    for (int j = 0; j < 16; ++j) {
      int col = m + 16 * j;
      float o = (sv[j] - mean) * r * gamma[col] + beta[col];
      hbf[(size_t)row * 256 + col] = f2bf(o);
    }
  }
}

// ---------------------------------------------------------------------------
// Output head FUSED (R15-proven)
// ---------------------------------------------------------------------------
__global__ __launch_bounds__(256) void head_fused_k(
    const ushort_t* __restrict__ hbf, const ushort_t* __restrict__ W1T,
    const float* __restrict__ b1, const float* __restrict__ W2,
    const float* __restrict__ b2, float* __restrict__ out, int M) {
  __shared__ __align__(16) ushort_t Als[64 * 64];
  __shared__ __align__(16) ushort_t Bls[128 * 64];
  int tid = threadIdx.x;
  int lane = tid & 63, w = tid >> 6;
  int quad = lane >> 4, m = lane & 15;
  int row0 = blockIdx.x * 64;
  float4v acc[8];
#pragma unroll
  for (int j = 0; j < 8; ++j) acc[j] = (float4v){0.f, 0.f, 0.f, 0.f};

  int srow = tid >> 3;
  int skc = (tid & 7) * 8;
  char* alsb = (char*)Als + w * 1024;
  char* blsb = (char*)Bls + w * 1024;

  for (int k0 = 0; k0 < 256; k0 += 64) {
#pragma unroll
    for (int q = 0; q < 2; ++q) {
      int r = row0 + q * 32 + srow;
      if (r < M) {
        const ushort_t* g = hbf + (size_t)r * 256 + k0 + skc;
        __builtin_amdgcn_global_load_lds((gas_p)g, (las_p)(alsb + q * 4096),
                                         16, 0, 0);
      }
    }
#pragma unroll
    for (int q = 0; q < 4; ++q) {
      const ushort_t* g = W1T + (size_t)(q * 32 + srow) * 256 + k0 + skc;
      __builtin_amdgcn_global_load_lds((gas_p)g, (las_p)(blsb + q * 4096), 16,
                                       0, 0);
    }
    __syncthreads();
#pragma unroll
    for (int ks = 0; ks < 64; ks += 32) {
      short8 a = *(const short8*)&Als[(w * 16 + m) * 64 + ks + quad * 8];
#pragma unroll
      for (int j = 0; j < 8; ++j) {
        short8 bj = *(const short8*)&Bls[(16 * j + m) * 64 + ks + quad * 8];
        acc[j] = __builtin_amdgcn_mfma_f32_16x16x32_bf16(a, bj, acc[j], 0, 0, 0);
      }
    }
    __syncthreads();
  }

#pragma unroll
  for (int rr = 0; rr < 4; ++rr) {
    int row = row0 + w * 16 + quad * 4 + rr;
    if (row >= M) continue;
    float p = 0.f;
#pragma unroll
    for (int j = 0; j < 8; ++j) {
      int col = m + 16 * j;
      float t = fmaxf(acc[j][rr] + b1[col], 0.f);
      p += t * W2[col];
    }
#pragma unroll
    for (int off = 1; off < 16; off <<= 1) p += __shfl_xor(p, off);
    if (m == 0) out[row] = p + b2[0];
  }
}

// ---------------------------------------------------------------------------
// FUSED edge phase v8: R8 structure + float2-packed math. After R8's
// ea-in-record cut fetch to 194.7 MB, the kernel shifted VALU-ward
// (VALUBusy 53->60, hbm rate 3.2->2.96 TB/s). The 16 scalar FMAs/edge/lane
// (8 dot + 8 accumulate) become 8 v_pk_fma_f32 by keeping the
// cvt_pk_f32_fp8 results as float2 vectors end-to-end. Same loads, same
// bytes, same semantics (pairwise dot reassociation only, ~1e-7).
// Degree-0: loop skipped -> l=0 -> clip(1e-12) -> agg=0, as the reference.
// ---------------------------------------------------------------------------
__global__ __launch_bounds__(256) void node_fused_k(
    const ushort_t* __restrict__ Q, const u8* __restrict__ KV8,
    const float* __restrict__ We_l, const int* __restrict__ rowptr,
    const int4* __restrict__ erec, ushort_t* __restrict__ agg, int n) {
  int node = (blockIdx.x * blockDim.x + threadIdx.x) >> 6;
  if (node >= n) return;
  int lane = threadIdx.x & 63;
  int hl = lane & 31;
  int slot = lane >> 5;
  ushort8v qu = *((const ushort8v*)(Q + (size_t)node * 256) + hl);
  float2v q2[4];
#pragma unroll
  for (int i = 0; i < 4; ++i)
    q2[i] = (float2v){bf2f(qu[2 * i]), bf2f(qu[2 * i + 1])};
  int start = rowptr[node], end = rowptr[node + 1];
  int hh = hl >> 2;
  float w0 = We_l[0 * 8 + hh], w1 = We_l[1 * 8 + hh], w2 = We_l[2 * 8 + hh];
  float l = 0.f;
  float2v acc2[4];
#pragma unroll
  for (int i = 0; i < 4; ++i) acc2[i] = (float2v){0.f, 0.f};

  int iters = (end - start + 1) >> 1;
  for (int it = 0; it < iters; ++it) {
    int p = start + 2 * it + slot;
    if (p < end) {
      int4 er = erec[p];
      const u8* base = KV8 + (size_t)er.x * 512;
      uint2 ku = *((const uint2*)base + hl);
      uint2 vu = *((const uint2*)(base + 256) + hl);
      float2v k0 = __builtin_amdgcn_cvt_pk_f32_fp8((int)ku.x, false);
      float2v k1 = __builtin_amdgcn_cvt_pk_f32_fp8((int)ku.x, true);
      float2v k2 = __builtin_amdgcn_cvt_pk_f32_fp8((int)ku.y, false);
      float2v k3 = __builtin_amdgcn_cvt_pk_f32_fp8((int)ku.y, true);
      float2v d2 = q2[0] * k0;
      d2 += q2[1] * k1;
      d2 += q2[2] * k2;
      d2 += q2[3] * k3;
      float d = d2[0] + d2[1];
      d += __shfl_xor(d, 1);
      d += __shfl_xor(d, 2);
      float e0 = bf2f((ushort_t)((u32)er.y & 0xFFFF));
      float e1 = bf2f((ushort_t)((u32)er.y >> 16));
      float e2 = bf2f((ushort_t)((u32)er.z & 0xFFFF));
      float bias = e0 * w0 + e1 * w1 + e2 * w2;
      float a = d * 0.17677669529663687f + bias;  // 1/sqrt(32)
      a = (a > 0.f) ? a : 0.2f * a;               // leaky_relu 0.2
      float wv = __expf(a);
      l += wv;
      float2v wv2 = (float2v){wv, wv};
      float2v v0 = __builtin_amdgcn_cvt_pk_f32_fp8((int)vu.x, false);
      float2v v1 = __builtin_amdgcn_cvt_pk_f32_fp8((int)vu.x, true);
      float2v v2 = __builtin_amdgcn_cvt_pk_f32_fp8((int)vu.y, false);
      float2v v3 = __builtin_amdgcn_cvt_pk_f32_fp8((int)vu.y, true);
      acc2[0] += v0 * wv2;
      acc2[1] += v1 * wv2;
      acc2[2] += v2 * wv2;
      acc2[3] += v3 * wv2;
    }
  }
  // merge the two half-wave partial sums
  l += __shfl_xor(l, 32);
  float inv = 1.f / fmaxf(l, 1e-12f);
  ushort8v o;
#pragma unroll
  for (int j = 0; j < 4; ++j) {
    float lo = (acc2[j][0] + __shfl_xor(acc2[j][0], 32)) * inv;
    float hi = (acc2[j][1] + __shfl_xor(acc2[j][1], 32)) * inv;
    o[2 * j] = f2bf(lo);
    o[2 * j + 1] = f2bf(hi);
  }
  if (slot == 0)
    *((ushort8v*)(agg + (size_t)node * 256) + hl) = o;
}

// ---------------------------------------------------------------------------
extern "C" void kernel_launch(void* const* d_in, const int* in_sizes, int n_in,
                              void* d_out, int out_size, void* d_ws,
                              size_t ws_size, hipStream_t stream) {
  const float* x = (const float*)d_in[0];
  const float* edge_attr = (const float*)d_in[1];
  const float* W_in = (const float*)d_in[2];
  const float* b_in = (const float*)d_in[3];
  const float* Wq = (const float*)d_in[4];
  const float* Wk = (const float*)d_in[5];
  const float* Wv = (const float*)d_in[6];
  const float* We = (const float*)d_in[7];
  const float* Wo = (const float*)d_in[8];
  const float* bo = (const float*)d_in[9];
  const float* Wm = (const float*)d_in[10];
  const float* bm = (const float*)d_in[11];
  const float* gamma = (const float*)d_in[12];
  const float* beta = (const float*)d_in[13];
  const float* W_h1 = (const float*)d_in[14];
  const float* b_h1 = (const float*)d_in[15];
  const float* W_h2 = (const float*)d_in[16];
  const float* b_h2 = (const float*)d_in[17];
  const u32* eidx_w = (const u32*)d_in[18];

  // ws layout (~118 MB)
  float* ws = (float*)d_ws;
  const size_t NH_ = (size_t)N_NODES * HDIM;
  ushort_t* hbf = (ushort_t*)ws;            // N x 256 bf16, persists
  ushort_t* Qbf = hbf + NH_;                // N x 256 bf16
  u8* KV8 = (u8*)(Qbf + NH_);               // N x 512 fp8 (K | V)
  ushort_t* aggbf = (ushort_t*)(KV8 + (size_t)N_NODES * 512);  // N x 256
  int* idxflag = (int*)(aggbf + NH_);
  int4* erec = (int4*)(idxflag + 4);        // E packed 16-B records
  int* rowptr = (int*)(erec + E_EDGES);     // N+1
  int* dcnt = rowptr + N_NODES + 1;         // N (hist)
  int* cursor = dcnt + N_NODES;             // N (fill) — zeroed together
  int* scanned = cursor + N_NODES;          // N
  int* bsum = scanned + N_NODES;            // 256
  float* bcomb = (float*)(bsum + 256);      // 3 x 256 fp32
  ushort_t* WT = (ushort_t*)(bcomb + 3 * 256);
  const size_t W64K = (size_t)HDIM * HDIM;
  const size_t W128K = (size_t)2 * HDIM * HDIM;
  ushort_t* WqkvT = WT;                     // 3 layers x (768 x 256)
  ushort_t* WmT = WqkvT + 3 * 3 * W64K;     // 3 layers x (256 x 512)
  ushort_t* Wh1T = WmT + 3 * W128K;
  // transient: consumed by fill_k before the first QKV gemm writes Qbf
  int* srcI = (int*)Qbf;
  int* dstI = srcI + E_EDGES;

  detect_idx_k<<<1, 256, 0, stream>>>(eidx_w, idxflag);
  hipMemsetAsync(dcnt, 0, (size_t)2 * N_NODES * sizeof(int), stream);
  convert_hist_k<<<(E_EDGES + 255) / 256, 256, 0, stream>>>(
      eidx_w, idxflag, srcI, dstI, dcnt, E_EDGES);
  const int nsb = (N_NODES + 255) / 256;
  scan1_k<<<nsb, 256, 0, stream>>>(dcnt, scanned, bsum, N_NODES);
  scan2_k<<<1, 256, 0, stream>>>(bsum, nsb);
  scan3_k<<<nsb, 256, 0, stream>>>(scanned, bsum, rowptr, N_NODES);
  fill_k<<<(E_EDGES + 255) / 256, 256, 0, stream>>>(
      srcI, dstI, edge_attr, rowptr, cursor, erec, E_EDGES);

  wtrans_all_k<<<dim3(32, 4, 13), 256, 0, stream>>>(Wq, Wk, Wv, Wm, W_h1,
                                                    WqkvT, WmT, Wh1T);
  wcomb_k<<<dim3(4, 4, 3), 256, 0, stream>>>(Wo, Wm, WmT);
  bcomb_k<<<dim3(1, 1, 3), 256, 0, stream>>>(bo, bm, Wm, bcomb);

  input_proj_k<<<(N_NODES + 31) / 32, 256, 0, stream>>>(x, W_in, b_in, hbf,
                                                        N_NODES);
  dim3 gqkv(768 / 64, (N_NODES + 127) / 128);  // (12, 391)
  const int gml = (N_NODES + 63) / 64;         // 782
  const int nodewave_grid = (N_NODES * 64 + 255) / 256;

  for (int l = 0; l < NLAYERS; ++l) {
    const float* We_l = We + (size_t)l * EDGED * NHEADS;

    // QKV = hbf @ [Wq|Wk|Wv] -> Q bf16, K/V fp8
    gemm_qkv_k<<<gqkv, 256, 0, stream>>>(
        hbf, WqkvT + (size_t)l * 3 * W64K, Qbf, KV8, N_NODES);
    // fused attention + softmax + aggregation (fp8 K/V, ea-in-record, pk-f32)
    node_fused_k<<<nodewave_grid, 256, 0, stream>>>(
        Qbf, KV8, We_l, rowptr, erec, aggbf, N_NODES);
    // hbf = LN(hbf + relu([hbf|agg]@Wm' + bcomb)) — GEMM+LN fused, in-place
    gemm_ln_k<<<gml, 256, 0, stream>>>(
        hbf, aggbf, WmT + (size_t)l * W128K, bcomb + l * 256,
        gamma + (size_t)l * HDIM, beta + (size_t)l * HDIM, N_NODES);
  }
  // fused output head
  head_fused_k<<<gml, 256, 0, stream>>>(hbf, Wh1T, b_h1, W_h2, b_h2,
                                        (float*)d_out, N_NODES);
}